// Round 17
// baseline (208.345 us; speedup 1.0000x reference)
//
#include <hip/hip_runtime.h>

#define EDGES 400000
#define NN 25000
#define NCH 288
#define EPA 64          // edges per block
#define NBIN_PAD 25024
#define SWS 68          // sw row stride in floats (17 float4, odd -> spread banks)

#define W1FRAG 16384   // 2 k2 * 16 nt * 64 lane * 8 el
#define W2FRAG 24576   // 8 k8 * 6 nt * 64 lane * 8 el

typedef float f32x4 __attribute__((ext_vector_type(4)));
typedef short short8 __attribute__((ext_vector_type(8)));

__device__ __forceinline__ unsigned short f2bf(float x) {          // RNE
    unsigned u = __float_as_uint(x);
    unsigned r = (u + 0x7fffu + ((u >> 16) & 1u)) >> 16;
    return (unsigned short)r;
}
__device__ __forceinline__ unsigned short f2bf_t(float x) {        // truncate
    return (unsigned short)(__float_as_uint(x) >> 16);
}
__device__ __forceinline__ float bf2f(unsigned short h) {
    return __uint_as_float(((unsigned)h) << 16);
}
__device__ __forceinline__ unsigned cvtpk(float a, float b) {      // 2xf32 -> 2xbf16 RNE
    unsigned r;
    asm("v_cvt_pk_bf16_f32 %0, %1, %2" : "=v"(r) : "v"(a), "v"(b));
    return r;
}
__device__ __forceinline__ float lowf(unsigned u)  { return __uint_as_float(u << 16); }
__device__ __forceinline__ float highf(unsigned u) { return __uint_as_float(u & 0xffff0000u); }

// ---------------- weight -> fragment-order bf16 hi/lo precompute ----------------
__global__ void k_wfrag(const float* __restrict__ W1, const float* __restrict__ W2,
                        unsigned short* __restrict__ w1h, unsigned short* __restrict__ w1l,
                        unsigned short* __restrict__ w2h, unsigned short* __restrict__ w2l) {
    int i = blockIdx.x * 256 + threadIdx.x;
    if (i < W1FRAG) {
        int j = i & 7, l = (i >> 3) & 63, nt = (i >> 9) & 15, k2 = (i >> 13) & 1;
        int n = nt * 16 + (l & 15), k = k2 * 32 + ((l >> 4) * 8) + j;
        float v = W1[k * 256 + n] * 0.125f;              // fold 1/sqrt(64)
        unsigned short hb = f2bf(v);
        w1h[i] = hb; w1l[i] = f2bf_t(v - bf2f(hb));
    } else if (i < W1FRAG + W2FRAG) {
        int i2 = i - W1FRAG;
        int j = i2 & 7, l = (i2 >> 3) & 63, r = i2 >> 9;  // r in [0,48)
        int nt = r % 6, k8 = r / 6;
        int n = nt * 16 + (l & 15), k = k8 * 32 + ((l >> 4) * 8) + j;
        float v = W2[k * 96 + n] * 0.015625f;            // fold 1/sqrt(256)*1/sqrt(16)
        unsigned short hb = f2bf(v);
        w2h[i2] = hb; w2l[i2] = f2bf_t(v - bf2f(hb));
    }
}

// ---------------- counting sort (dst-ordered edges), parallel 2-level scan ----------------
__global__ void k_hist(const int* __restrict__ edst, unsigned* __restrict__ cnt) {
    int i = blockIdx.x * 256 + threadIdx.x;
    if (i < EDGES) atomicAdd(&cnt[edst[i]], 1u);
}

__global__ __launch_bounds__(1024) void k_scanA(const unsigned* __restrict__ cnt,
                                                unsigned* __restrict__ cur,
                                                unsigned* __restrict__ tot) {
    __shared__ unsigned s_wt[16];
    const int t = threadIdx.x, lane = t & 63, wid = t >> 6;
    int i = blockIdx.x * 1024 + t;
    unsigned v = (i < NN) ? cnt[i] : 0u;
    unsigned incl = v;
    #pragma unroll
    for (int d = 1; d < 64; d <<= 1) {
        unsigned u = __shfl_up(incl, d);
        if (lane >= d) incl += u;
    }
    if (lane == 63) s_wt[wid] = incl;
    __syncthreads();
    if (wid == 0 && lane < 16) {
        unsigned wincl = s_wt[lane];
        #pragma unroll
        for (int d = 1; d < 16; d <<= 1) {
            unsigned u = __shfl_up(wincl, d);
            if (lane >= d) wincl += u;
        }
        s_wt[lane] = wincl;
    }
    __syncthreads();
    unsigned waveoff = (wid > 0) ? s_wt[wid - 1] : 0u;
    if (i < NN) cur[i] = waveoff + incl - v;
    if (t == 0) tot[blockIdx.x] = s_wt[15];
}

__global__ void k_scanB(unsigned* __restrict__ tot, unsigned* __restrict__ toff, int nblk) {
    int lane = threadIdx.x;
    unsigned v = (lane < nblk) ? tot[lane] : 0u;
    unsigned incl = v;
    #pragma unroll
    for (int d = 1; d < 64; d <<= 1) {
        unsigned u = __shfl_up(incl, d);
        if (lane >= d) incl += u;
    }
    if (lane < nblk) toff[lane] = incl - v;
}

__global__ __launch_bounds__(1024) void k_scanC(unsigned* __restrict__ cur,
                                                const unsigned* __restrict__ toff) {
    int i = blockIdx.x * 1024 + threadIdx.x;
    if (i < NN) cur[i] += toff[blockIdx.x];
}

__global__ void k_perm(const int* __restrict__ edst, unsigned* __restrict__ cur,
                       unsigned* __restrict__ perm) {
    int i = blockIdx.x * 256 + threadIdx.x;
    if (i < EDGES) {
        unsigned p = atomicAdd(&cur[edst[i]], 1u);
        perm[p] = (unsigned)i;
    }
}

// ---------------- fused conv: eighth-pipeline MLP + in-block TP (5 blocks/CU) ----------------
struct SMemU {
    union {
        struct __align__(16) {
            unsigned short a1h[EPA * 64];   // 8 KB   etype hi [e][k] swizzled (128B rows)
            unsigned short a1l[EPA * 64];   // 8 KB
            unsigned short a2h[EPA * 40];   // 5 KB   h eighth: 80B rows (20 dwords), NO swizzle
            unsigned short a2l[EPA * 40];   // 5 KB
        };
        float sw[96 * SWS];                 // 26.1 KB  w[c][e], overlay after MFMA phases
    };
};

template <bool SORTED>
__global__ __launch_bounds__(256) void conv_fused(
    const int* __restrict__ esrc, const int* __restrict__ edst,
    const float* __restrict__ nemb, const float* __restrict__ etype,
    const unsigned short* __restrict__ w1h, const unsigned short* __restrict__ w1l,
    const unsigned short* __restrict__ w2h, const unsigned short* __restrict__ w2l,
    const unsigned* __restrict__ perm,
    float* __restrict__ out)
{
    __shared__ SMemU U;                               // 26.6 KB
    __shared__ __align__(16) float gsm[2][9][SWS];    // 4.9 KB  [b][gi][e]
    __shared__ int s_eidx[EPA], s_dst[EPA];
    __shared__ unsigned s_mlo, s_mhi;

    const int t = threadIdx.x;
    const int lane = t & 63, w = t >> 6;
    const int g = lane >> 4, ln15 = lane & 15;
    const size_t slot0 = (size_t)blockIdx.x * EPA;

    if (t < EPA) {
        int e = SORTED ? (int)perm[slot0 + t] : (int)(slot0 + t);
        s_eidx[t] = e;
        s_dst[t] = edst[e];
    }
    __syncthreads();

    // ---- phase 1: stage etype tile -> a1 (all threads); geom (t<128); mask (wave 2) ----
    #pragma unroll
    for (int i = 0; i < 4; ++i) {
        int f4 = t + 256 * i;                  // 0..1023
        int row = f4 >> 4, q = f4 & 15;
        const float4* src = (const float4*)(etype + (size_t)s_eidx[row] * 64);
        float4 v = src[q];
        unsigned hp01 = cvtpk(v.x, v.y), hp23 = cvtpk(v.z, v.w);
        float lo0 = v.x - lowf(hp01), lo1 = v.y - highf(hp01);
        float lo2 = v.z - lowf(hp23), lo3 = v.w - highf(hp23);
        unsigned lp01 = cvtpk(lo0, lo1), lp23 = cvtpk(lo2, lo3);
        int boff = row * 128 + ((q * 8) ^ ((row & 7) << 4));
        *(uint2*)((char*)U.a1h + boff) = make_uint2(hp01, hp23);
        *(uint2*)((char*)U.a1l + boff) = make_uint2(lp01, lp23);
    }
    if (t < EPA * 2) {
        int e = t >> 1, b = t & 1;
        int sn = esrc[s_eidx[e]], dn = s_dst[e];
        const float* xp = nemb + ((size_t)b * NN + sn) * 3;
        const float* yp = nemb + ((size_t)b * NN + dn) * 3;
        float x0 = xp[0], x1 = xp[1], x2 = xp[2];
        float y0 = yp[0], y1 = yp[1], y2 = yp[2];
        const float inv3 = 0.5773502691896258f;
        const float inv2 = 0.7071067811865476f;
        const float inv6 = 0.4082482904638630f;
        gsm[b][0][e] = (x0*y0 + x1*y1 + x2*y2) * inv3;
        gsm[b][1][e] = (x1*y2 - x2*y1) * inv2;
        gsm[b][2][e] = (x2*y0 - x0*y2) * inv2;
        gsm[b][3][e] = (x0*y1 - x1*y0) * inv2;
        gsm[b][4][e] = (x0*y1 + x1*y0) * inv2;
        gsm[b][5][e] = (x1*y2 + x2*y1) * inv2;
        gsm[b][6][e] = (x0*y2 + x2*y0) * inv2;
        gsm[b][7][e] = (x0*y0 - x1*y1) * inv2;
        gsm[b][8][e] = (2.0f*x2*y2 - x0*y0 - x1*y1) * inv6;
    } else if (t < 192) {
        int e = t - 128;                                    // wave 2, lane = slot
        bool flag = (e > 0) && (s_dst[e] != s_dst[e - 1]);
        unsigned long long bal = __ballot(flag);
        if (e == 0) { s_mlo = (unsigned)bal; s_mhi = (unsigned)(bal >> 32); }
    }
    __syncthreads();

    // ---- MLP eighth pipeline: phase ph = layer-2 k-step kg ----
    const int mh = w & 1, nb = 3 * (w >> 1);
    const int np = w & 1, ehf = w >> 1;
    f32x4 acc2[2][3];
    #pragma unroll
    for (int mm = 0; mm < 2; ++mm)
        #pragma unroll
        for (int n = 0; n < 3; ++n)
            #pragma unroll
            for (int r = 0; r < 4; ++r) acc2[mm][n][r] = 0.f;

    #pragma unroll
    for (int ph = 0; ph < 8; ++ph) {
        // ---- layer 1 (eighth): n-tile 2*ph + np, 2 e-tiles ----
        f32x4 acc1[2];
        #pragma unroll
        for (int mi = 0; mi < 2; ++mi)
            #pragma unroll
            for (int r = 0; r < 4; ++r) acc1[mi][r] = 0.f;

        #pragma unroll
        for (int k2 = 0; k2 < 2; ++k2) {
            int idx = ((k2 * 16 + 2 * ph + np) * 64 + lane) * 8;
            short8 wah = *(const short8*)(w1h + idx);
            short8 wal = *(const short8*)(w1l + idx);
            #pragma unroll
            for (int mi = 0; mi < 2; ++mi) {
                int row = (2 * ehf + mi) * 16 + ln15;
                int boff = row * 128 + (((k2 * 64) + g * 16) ^ ((row & 7) << 4));
                short8 eth = *(const short8*)((const char*)U.a1h + boff);
                short8 etl = *(const short8*)((const char*)U.a1l + boff);
                acc1[mi] = __builtin_amdgcn_mfma_f32_16x16x32_bf16(wah, eth, acc1[mi], 0, 0, 0);
                acc1[mi] = __builtin_amdgcn_mfma_f32_16x16x32_bf16(wal, eth, acc1[mi], 0, 0, 0);
                acc1[mi] = __builtin_amdgcn_mfma_f32_16x16x32_bf16(wah, etl, acc1[mi], 0, 0, 0);
            }
        }

        // ---- silu + packed split -> h eighth buffer (80B rows, stride-20-dword, no swz) ----
        #pragma unroll
        for (int mi = 0; mi < 2; ++mi) {
            float p0 = acc1[mi][0], p1 = acc1[mi][1], p2 = acc1[mi][2], p3 = acc1[mi][3];
            float s0 = p0 * __builtin_amdgcn_rcpf(1.f + __expf(-p0));
            float s1 = p1 * __builtin_amdgcn_rcpf(1.f + __expf(-p1));
            float s2 = p2 * __builtin_amdgcn_rcpf(1.f + __expf(-p2));
            float s3 = p3 * __builtin_amdgcn_rcpf(1.f + __expf(-p3));
            unsigned hp0 = cvtpk(s0, s1), hp1 = cvtpk(s2, s3);
            float lo0 = s0 - lowf(hp0), lo1 = s1 - highf(hp0);
            float lo2 = s2 - lowf(hp1), lo3 = s3 - highf(hp1);
            unsigned lp0 = cvtpk(lo0, lo1), lp1 = cvtpk(lo2, lo3);
            int e = (2 * ehf + mi) * 16 + ln15;
            int boff = e * 80 + np * 32 + g * 8;          // 8B-aligned; rows 20 dwords apart
            *(uint2*)((char*)U.a2h + boff) = make_uint2(hp0, hp1);
            *(uint2*)((char*)U.a2l + boff) = make_uint2(lp0, lp1);
        }
        __syncthreads();

        // ---- layer 2 (eighth): single k-step kg = ph ----
        {
            short8 bh[3], bl[3];
            #pragma unroll
            for (int n = 0; n < 3; ++n) {
                int idx = ((ph * 6 + nb + n) * 64 + lane) * 8;
                bh[n] = *(const short8*)(w2h + idx);
                bl[n] = *(const short8*)(w2l + idx);
            }
            #pragma unroll
            for (int mm = 0; mm < 2; ++mm) {
                int row = (2 * mh + mm) * 16 + ln15;
                int boff = row * 80 + g * 16;             // 16B-aligned (80 = 16*5)
                short8 ah = *(const short8*)((const char*)U.a2h + boff);
                short8 al = *(const short8*)((const char*)U.a2l + boff);
                #pragma unroll
                for (int n = 0; n < 3; ++n) {
                    acc2[mm][n] = __builtin_amdgcn_mfma_f32_16x16x32_bf16(ah, bh[n], acc2[mm][n], 0, 0, 0);
                    acc2[mm][n] = __builtin_amdgcn_mfma_f32_16x16x32_bf16(ah, bl[n], acc2[mm][n], 0, 0, 0);
                    acc2[mm][n] = __builtin_amdgcn_mfma_f32_16x16x32_bf16(al, bh[n], acc2[mm][n], 0, 0, 0);
                }
            }
        }
        __syncthreads();   // a2 consumed; next phase overwrites (a1/a2 dead after ph=7)
    }

    // ---- write w -> sw[c][e] overlay (a1+a2 dead; loop-end barrier passed) ----
    #pragma unroll
    for (int mm = 0; mm < 2; ++mm) {
        #pragma unroll
        for (int n = 0; n < 3; ++n) {
            int c = (nb + n) * 16 + ln15;
            int e_base = (2 * mh + mm) * 16 + g * 4;         // f32x4 over r
            *(f32x4*)&U.sw[c * SWS + e_base] = acc2[mm][n];
        }
    }
    __syncthreads();

    // ---- TP + run-grouped scatter over the block's 64 sorted slots ----
    {
        unsigned mlo = __builtin_amdgcn_readfirstlane(s_mlo);
        unsigned mhi = __builtin_amdgcn_readfirstlane(s_mhi);
        for (int idx = t; idx < NCH * 2; idx += 256) {
            int b = idx >= NCH;
            int c = idx - b * NCH;
            unsigned wi, gi;
            if (c < 32)       { wi = c;                          gi = 0; }
            else if (c < 128) { unsigned q = c - 32;  wi = 32 + q / 3u; gi = 1 + q % 3u; }
            else              { unsigned q = c - 128; wi = 64 + q / 5u; gi = 4 + q % 5u; }
            float* base = out + (size_t)b * NN * NCH + c;
            float acc = 0.f;
            int rs = 0;
            #pragma unroll
            for (int q4 = 0; q4 < 16; ++q4) {
                f32x4 wv = *(const f32x4*)&U.sw[wi * SWS + q4 * 4];
                f32x4 gv = *(const f32x4*)&gsm[b][gi][q4 * 4];
                unsigned word = (q4 < 8) ? mlo : mhi;
                unsigned nib = (word >> ((q4 * 4) & 31)) & 0xFu;
                if (nib == 0u) {                               // common case: no boundary
                    acc = fmaf(wv[0], gv[0], acc);
                    acc = fmaf(wv[1], gv[1], acc);
                    acc = fmaf(wv[2], gv[2], acc);
                    acc = fmaf(wv[3], gv[3], acc);
                } else {
                    #pragma unroll
                    for (int j = 0; j < 4; ++j) {
                        int e = q4 * 4 + j;
                        if (e && ((nib >> j) & 1u)) {
                            float* addr = base + (size_t)s_dst[e - 1] * NCH;
                            if (SORTED && rs > 0) *addr = acc;     // interior run
                            else atomicAdd(addr, acc);             // boundary run
                            acc = 0.f; rs = e;
                        }
                        acc = fmaf(wv[j], gv[j], acc);
                    }
                }
            }
            atomicAdd(base + (size_t)s_dst[EPA - 1] * NCH, acc);   // last run: boundary
        }
    }
}

extern "C" void kernel_launch(void* const* d_in, const int* in_sizes, int n_in,
                              void* d_out, int out_size, void* d_ws, size_t ws_size,
                              hipStream_t stream) {
    const int*   esrc  = (const int*)d_in[0];
    const int*   edst  = (const int*)d_in[1];
    const float* nemb  = (const float*)d_in[2];
    const float* etype = (const float*)d_in[3];
    const float* W1    = (const float*)d_in[4];
    const float* W2    = (const float*)d_in[5];
    float* out = (float*)d_out;

    hipMemsetAsync(out, 0, (size_t)out_size * sizeof(float), stream);

    const size_t frag_bytes = (size_t)(2 * W1FRAG + 2 * W2FRAG) * sizeof(unsigned short);
    unsigned short* w1h = (unsigned short*)d_ws;
    unsigned short* w1l = w1h + W1FRAG;
    unsigned short* w2h = w1l + W1FRAG;
    unsigned short* w2l = w2h + W2FRAG;

    const int NSCAN = (NN + 1023) / 1024;             // 25
    size_t o_cnt  = frag_bytes;
    size_t o_cur  = o_cnt + (size_t)NBIN_PAD * 4;
    size_t o_tot  = o_cur + (size_t)NBIN_PAD * 4;
    size_t o_toff = o_tot + 128;
    size_t o_perm = o_toff + 128;
    size_t need_sort = o_perm + (size_t)EDGES * 4;

    k_wfrag<<<(W1FRAG + W2FRAG + 255) / 256, 256, 0, stream>>>(W1, W2, w1h, w1l, w2h, w2l);

    if (ws_size >= need_sort) {
        unsigned* cnt  = (unsigned*)((char*)d_ws + o_cnt);
        unsigned* cur  = (unsigned*)((char*)d_ws + o_cur);
        unsigned* tot  = (unsigned*)((char*)d_ws + o_tot);
        unsigned* toff = (unsigned*)((char*)d_ws + o_toff);
        unsigned* perm = (unsigned*)((char*)d_ws + o_perm);
        hipMemsetAsync(cnt, 0, (size_t)NBIN_PAD * 4, stream);
        k_hist<<<(EDGES + 255) / 256, 256, 0, stream>>>(edst, cnt);
        k_scanA<<<NSCAN, 1024, 0, stream>>>(cnt, cur, tot);
        k_scanB<<<1, 64, 0, stream>>>(tot, toff, NSCAN);
        k_scanC<<<NSCAN, 1024, 0, stream>>>(cur, toff);
        k_perm<<<(EDGES + 255) / 256, 256, 0, stream>>>(edst, cur, perm);
        conv_fused<true><<<EDGES / EPA, 256, 0, stream>>>(
            esrc, edst, nemb, etype, w1h, w1l, w2h, w2l, perm, out);
    } else {
        conv_fused<false><<<EDGES / EPA, 256, 0, stream>>>(
            esrc, edst, nemb, etype, w1h, w1l, w2h, w2l, nullptr, out);
    }
}

// Round 18
// 197.232 us; speedup vs baseline: 1.0563x; 1.0563x over previous
//
#include <hip/hip_runtime.h>

#define EDGES 400000
#define NN 25000
#define NCH 288
#define EPA 64          // edges per block
#define NBIN_PAD 25024
#define SWS 68          // sw row stride in floats (17 float4, odd -> spread banks)

#define W1FRAG 16384   // 2 k2 * 16 nt * 64 lane * 8 el
#define W2FRAG 24576   // 8 k8 * 6 nt * 64 lane * 8 el

typedef float f32x4 __attribute__((ext_vector_type(4)));
typedef short short8 __attribute__((ext_vector_type(8)));

__device__ __forceinline__ unsigned short f2bf(float x) {          // RNE
    unsigned u = __float_as_uint(x);
    unsigned r = (u + 0x7fffu + ((u >> 16) & 1u)) >> 16;
    return (unsigned short)r;
}
__device__ __forceinline__ unsigned short f2bf_t(float x) {        // truncate
    return (unsigned short)(__float_as_uint(x) >> 16);
}
__device__ __forceinline__ float bf2f(unsigned short h) {
    return __uint_as_float(((unsigned)h) << 16);
}
__device__ __forceinline__ unsigned cvtpk(float a, float b) {      // 2xf32 -> 2xbf16 RNE
    unsigned r;
    asm("v_cvt_pk_bf16_f32 %0, %1, %2" : "=v"(r) : "v"(a), "v"(b));
    return r;
}
__device__ __forceinline__ float lowf(unsigned u)  { return __uint_as_float(u << 16); }
__device__ __forceinline__ float highf(unsigned u) { return __uint_as_float(u & 0xffff0000u); }

// ---------------- weight -> fragment-order bf16 hi/lo precompute ----------------
__global__ void k_wfrag(const float* __restrict__ W1, const float* __restrict__ W2,
                        unsigned short* __restrict__ w1h, unsigned short* __restrict__ w1l,
                        unsigned short* __restrict__ w2h, unsigned short* __restrict__ w2l) {
    int i = blockIdx.x * 256 + threadIdx.x;
    if (i < W1FRAG) {
        int j = i & 7, l = (i >> 3) & 63, nt = (i >> 9) & 15, k2 = (i >> 13) & 1;
        int n = nt * 16 + (l & 15), k = k2 * 32 + ((l >> 4) * 8) + j;
        float v = W1[k * 256 + n] * 0.125f;              // fold 1/sqrt(64)
        unsigned short hb = f2bf(v);
        w1h[i] = hb; w1l[i] = f2bf_t(v - bf2f(hb));
    } else if (i < W1FRAG + W2FRAG) {
        int i2 = i - W1FRAG;
        int j = i2 & 7, l = (i2 >> 3) & 63, r = i2 >> 9;  // r in [0,48)
        int nt = r % 6, k8 = r / 6;
        int n = nt * 16 + (l & 15), k = k8 * 32 + ((l >> 4) * 8) + j;
        float v = W2[k * 96 + n] * 0.015625f;            // fold 1/sqrt(256)*1/sqrt(16)
        unsigned short hb = f2bf(v);
        w2h[i2] = hb; w2l[i2] = f2bf_t(v - bf2f(hb));
    }
}

// ---------------- counting sort (dst-ordered edges), parallel 2-level scan ----------------
__global__ void k_hist(const int* __restrict__ edst, unsigned* __restrict__ cnt) {
    int i = blockIdx.x * 256 + threadIdx.x;
    if (i < EDGES) atomicAdd(&cnt[edst[i]], 1u);
}

__global__ __launch_bounds__(1024) void k_scanA(const unsigned* __restrict__ cnt,
                                                unsigned* __restrict__ cur,
                                                unsigned* __restrict__ tot) {
    __shared__ unsigned s_wt[16];
    const int t = threadIdx.x, lane = t & 63, wid = t >> 6;
    int i = blockIdx.x * 1024 + t;
    unsigned v = (i < NN) ? cnt[i] : 0u;
    unsigned incl = v;
    #pragma unroll
    for (int d = 1; d < 64; d <<= 1) {
        unsigned u = __shfl_up(incl, d);
        if (lane >= d) incl += u;
    }
    if (lane == 63) s_wt[wid] = incl;
    __syncthreads();
    if (wid == 0 && lane < 16) {
        unsigned wincl = s_wt[lane];
        #pragma unroll
        for (int d = 1; d < 16; d <<= 1) {
            unsigned u = __shfl_up(wincl, d);
            if (lane >= d) wincl += u;
        }
        s_wt[lane] = wincl;
    }
    __syncthreads();
    unsigned waveoff = (wid > 0) ? s_wt[wid - 1] : 0u;
    if (i < NN) cur[i] = waveoff + incl - v;
    if (t == 0) tot[blockIdx.x] = s_wt[15];
}

__global__ void k_scanB(unsigned* __restrict__ tot, unsigned* __restrict__ toff, int nblk) {
    int lane = threadIdx.x;
    unsigned v = (lane < nblk) ? tot[lane] : 0u;
    unsigned incl = v;
    #pragma unroll
    for (int d = 1; d < 64; d <<= 1) {
        unsigned u = __shfl_up(incl, d);
        if (lane >= d) incl += u;
    }
    if (lane < nblk) toff[lane] = incl - v;
}

__global__ __launch_bounds__(1024) void k_scanC(unsigned* __restrict__ cur,
                                                const unsigned* __restrict__ toff) {
    int i = blockIdx.x * 1024 + threadIdx.x;
    if (i < NN) cur[i] += toff[blockIdx.x];
}

__global__ void k_perm(const int* __restrict__ edst, unsigned* __restrict__ cur,
                       unsigned* __restrict__ perm) {
    int i = blockIdx.x * 256 + threadIdx.x;
    if (i < EDGES) {
        unsigned p = atomicAdd(&cur[edst[i]], 1u);
        perm[p] = (unsigned)i;
    }
}

// ---------------- fused conv: quarter-pipeline MLP + in-block TP (round-15 structure) ----------------
struct SMemU {
    union {
        struct __align__(16) {
            unsigned short a1h[EPA * 64];   // 8 KB  etype hi [e][k] swizzled
            unsigned short a1l[EPA * 64];   // 8 KB
            unsigned short a2h[EPA * 64];   // 8 KB  h quarter hi
            unsigned short a2l[EPA * 64];   // 8 KB
        };
        float sw[96 * SWS];                 // 26.1 KB  w[c][e], overlay after MFMA phases
    };
};

template <bool SORTED>
__global__ __launch_bounds__(256) void conv_fused(
    const int* __restrict__ esrc, const int* __restrict__ edst,
    const float* __restrict__ nemb, const float* __restrict__ etype,
    const unsigned short* __restrict__ w1h, const unsigned short* __restrict__ w1l,
    const unsigned short* __restrict__ w2h, const unsigned short* __restrict__ w2l,
    const unsigned* __restrict__ perm,
    float* __restrict__ out)
{
    __shared__ SMemU U;                               // 32 KB
    __shared__ __align__(16) float gsm[2][9][SWS];    // 4.9 KB  [b][gi][e]
    __shared__ int s_eidx[EPA], s_dst[EPA];
    __shared__ unsigned s_mlo, s_mhi;

    const int t = threadIdx.x;
    const int lane = t & 63, w = t >> 6;
    const int g = lane >> 4, ln15 = lane & 15;
    const size_t slot0 = (size_t)blockIdx.x * EPA;

    if (t < EPA) {
        int e = SORTED ? (int)perm[slot0 + t] : (int)(slot0 + t);
        s_eidx[t] = e;
        s_dst[t] = edst[e];
    }
    __syncthreads();

    // ---- phase 1: stage etype tile -> a1 (all threads); geom (t<128); mask (wave 2) ----
    #pragma unroll
    for (int i = 0; i < 4; ++i) {
        int f4 = t + 256 * i;                  // 0..1023
        int row = f4 >> 4, q = f4 & 15;
        const float4* src = (const float4*)(etype + (size_t)s_eidx[row] * 64);
        float4 v = src[q];
        unsigned hp01 = cvtpk(v.x, v.y), hp23 = cvtpk(v.z, v.w);
        float lo0 = v.x - lowf(hp01), lo1 = v.y - highf(hp01);
        float lo2 = v.z - lowf(hp23), lo3 = v.w - highf(hp23);
        unsigned lp01 = cvtpk(lo0, lo1), lp23 = cvtpk(lo2, lo3);
        int boff = row * 128 + ((q * 8) ^ ((row & 7) << 4));
        *(uint2*)((char*)U.a1h + boff) = make_uint2(hp01, hp23);
        *(uint2*)((char*)U.a1l + boff) = make_uint2(lp01, lp23);
    }
    if (t < EPA * 2) {
        int e = t >> 1, b = t & 1;
        int sn = esrc[s_eidx[e]], dn = s_dst[e];
        const float* xp = nemb + ((size_t)b * NN + sn) * 3;
        const float* yp = nemb + ((size_t)b * NN + dn) * 3;
        float x0 = xp[0], x1 = xp[1], x2 = xp[2];
        float y0 = yp[0], y1 = yp[1], y2 = yp[2];
        const float inv3 = 0.5773502691896258f;
        const float inv2 = 0.7071067811865476f;
        const float inv6 = 0.4082482904638630f;
        gsm[b][0][e] = (x0*y0 + x1*y1 + x2*y2) * inv3;
        gsm[b][1][e] = (x1*y2 - x2*y1) * inv2;
        gsm[b][2][e] = (x2*y0 - x0*y2) * inv2;
        gsm[b][3][e] = (x0*y1 - x1*y0) * inv2;
        gsm[b][4][e] = (x0*y1 + x1*y0) * inv2;
        gsm[b][5][e] = (x1*y2 + x2*y1) * inv2;
        gsm[b][6][e] = (x0*y2 + x2*y0) * inv2;
        gsm[b][7][e] = (x0*y0 - x1*y1) * inv2;
        gsm[b][8][e] = (2.0f*x2*y2 - x0*y0 - x1*y1) * inv6;
    } else if (t < 192) {
        int e = t - 128;                                    // wave 2, lane = slot
        bool flag = (e > 0) && (s_dst[e] != s_dst[e - 1]);
        unsigned long long bal = __ballot(flag);
        if (e == 0) { s_mlo = (unsigned)bal; s_mhi = (unsigned)(bal >> 32); }
    }
    __syncthreads();

    // ---- MLP quarter pipeline ----
    const int mh = w & 1, nb = 3 * (w >> 1);
    f32x4 acc2[2][3];
    #pragma unroll
    for (int mm = 0; mm < 2; ++mm)
        #pragma unroll
        for (int n = 0; n < 3; ++n)
            #pragma unroll
            for (int r = 0; r < 4; ++r) acc2[mm][n][r] = 0.f;

    #pragma unroll
    for (int qt = 0; qt < 4; ++qt) {
        f32x4 acc1[4];
        #pragma unroll
        for (int m = 0; m < 4; ++m)
            #pragma unroll
            for (int r = 0; r < 4; ++r) acc1[m][r] = 0.f;

        #pragma unroll
        for (int k2 = 0; k2 < 2; ++k2) {
            int idx = ((k2 * 16 + 4 * qt + w) * 64 + lane) * 8;
            short8 wah = *(const short8*)(w1h + idx);
            short8 wal = *(const short8*)(w1l + idx);
            #pragma unroll
            for (int m = 0; m < 4; ++m) {
                int row = m * 16 + ln15;
                int boff = row * 128 + (((k2 * 64) + g * 16) ^ ((row & 7) << 4));
                short8 eth = *(const short8*)((const char*)U.a1h + boff);
                short8 etl = *(const short8*)((const char*)U.a1l + boff);
                acc1[m] = __builtin_amdgcn_mfma_f32_16x16x32_bf16(wah, eth, acc1[m], 0, 0, 0);
                acc1[m] = __builtin_amdgcn_mfma_f32_16x16x32_bf16(wal, eth, acc1[m], 0, 0, 0);
                acc1[m] = __builtin_amdgcn_mfma_f32_16x16x32_bf16(wah, etl, acc1[m], 0, 0, 0);
            }
        }

        #pragma unroll
        for (int m = 0; m < 4; ++m) {
            float p0 = acc1[m][0], p1 = acc1[m][1], p2 = acc1[m][2], p3 = acc1[m][3];
            float s0 = p0 * __builtin_amdgcn_rcpf(1.f + __expf(-p0));
            float s1 = p1 * __builtin_amdgcn_rcpf(1.f + __expf(-p1));
            float s2 = p2 * __builtin_amdgcn_rcpf(1.f + __expf(-p2));
            float s3 = p3 * __builtin_amdgcn_rcpf(1.f + __expf(-p3));
            unsigned hp0 = cvtpk(s0, s1), hp1 = cvtpk(s2, s3);
            float lo0 = s0 - lowf(hp0), lo1 = s1 - highf(hp0);
            float lo2 = s2 - lowf(hp1), lo3 = s3 - highf(hp1);
            unsigned lp0 = cvtpk(lo0, lo1), lp1 = cvtpk(lo2, lo3);
            int e = m * 16 + ln15;
            int boff = e * 128 + ((w * 32 + g * 8) ^ ((ln15 & 7) << 4));
            *(uint2*)((char*)U.a2h + boff) = make_uint2(hp0, hp1);
            *(uint2*)((char*)U.a2l + boff) = make_uint2(lp0, lp1);
        }
        __syncthreads();

        #pragma unroll
        for (int kk = 0; kk < 2; ++kk) {
            int kg = 2 * qt + kk;
            short8 bh[3], bl[3];
            #pragma unroll
            for (int n = 0; n < 3; ++n) {
                int idx = ((kg * 6 + nb + n) * 64 + lane) * 8;
                bh[n] = *(const short8*)(w2h + idx);
                bl[n] = *(const short8*)(w2l + idx);
            }
            #pragma unroll
            for (int mm = 0; mm < 2; ++mm) {
                int row = (2 * mh + mm) * 16 + ln15;
                int boff = row * 128 + ((kk * 64 + g * 16) ^ ((ln15 & 7) << 4));
                short8 ah = *(const short8*)((const char*)U.a2h + boff);
                short8 al = *(const short8*)((const char*)U.a2l + boff);
                #pragma unroll
                for (int n = 0; n < 3; ++n) {
                    acc2[mm][n] = __builtin_amdgcn_mfma_f32_16x16x32_bf16(ah, bh[n], acc2[mm][n], 0, 0, 0);
                    acc2[mm][n] = __builtin_amdgcn_mfma_f32_16x16x32_bf16(ah, bl[n], acc2[mm][n], 0, 0, 0);
                    acc2[mm][n] = __builtin_amdgcn_mfma_f32_16x16x32_bf16(al, bh[n], acc2[mm][n], 0, 0, 0);
                }
            }
        }
        __syncthreads();   // a2 consumed; next quarter overwrites (a1/a2 dead after qt=3)
    }

    // ---- write w -> sw[c][e] overlay (a1+a2 dead; loop-end barrier passed) ----
    #pragma unroll
    for (int mm = 0; mm < 2; ++mm) {
        #pragma unroll
        for (int n = 0; n < 3; ++n) {
            int c = (nb + n) * 16 + ln15;
            int e_base = (2 * mh + mm) * 16 + g * 4;         // f32x4 over r
            *(f32x4*)&U.sw[c * SWS + e_base] = acc2[mm][n];
        }
    }
    __syncthreads();

    // ---- TP + run-grouped scatter over the block's 64 sorted slots ----
    {
        unsigned mlo = __builtin_amdgcn_readfirstlane(s_mlo);
        unsigned mhi = __builtin_amdgcn_readfirstlane(s_mhi);
        for (int idx = t; idx < NCH * 2; idx += 256) {
            int b = idx >= NCH;
            int c = idx - b * NCH;
            unsigned wi, gi;
            if (c < 32)       { wi = c;                          gi = 0; }
            else if (c < 128) { unsigned q = c - 32;  wi = 32 + q / 3u; gi = 1 + q % 3u; }
            else              { unsigned q = c - 128; wi = 64 + q / 5u; gi = 4 + q % 5u; }
            float* base = out + (size_t)b * NN * NCH + c;
            float acc = 0.f;
            int rs = 0;
            #pragma unroll
            for (int q4 = 0; q4 < 16; ++q4) {
                f32x4 wv = *(const f32x4*)&U.sw[wi * SWS + q4 * 4];
                f32x4 gv = *(const f32x4*)&gsm[b][gi][q4 * 4];
                // wave-uniform nibble: boundary bits for edges q4*4..q4*4+3
                unsigned word = (q4 < 8) ? mlo : mhi;
                unsigned nib = (word >> ((q4 * 4) & 31)) & 0xFu;
                if (nib == 0u) {                               // common case: no boundary
                    acc = fmaf(wv[0], gv[0], acc);
                    acc = fmaf(wv[1], gv[1], acc);
                    acc = fmaf(wv[2], gv[2], acc);
                    acc = fmaf(wv[3], gv[3], acc);
                } else {
                    #pragma unroll
                    for (int j = 0; j < 4; ++j) {
                        int e = q4 * 4 + j;
                        if (e && ((nib >> j) & 1u)) {
                            float* addr = base + (size_t)s_dst[e - 1] * NCH;
                            if (SORTED && rs > 0) *addr = acc;     // interior run
                            else atomicAdd(addr, acc);             // boundary run
                            acc = 0.f; rs = e;
                        }
                        acc = fmaf(wv[j], gv[j], acc);
                    }
                }
            }
            atomicAdd(base + (size_t)s_dst[EPA - 1] * NCH, acc);   // last run: boundary
        }
    }
}

extern "C" void kernel_launch(void* const* d_in, const int* in_sizes, int n_in,
                              void* d_out, int out_size, void* d_ws, size_t ws_size,
                              hipStream_t stream) {
    const int*   esrc  = (const int*)d_in[0];
    const int*   edst  = (const int*)d_in[1];
    const float* nemb  = (const float*)d_in[2];
    const float* etype = (const float*)d_in[3];
    const float* W1    = (const float*)d_in[4];
    const float* W2    = (const float*)d_in[5];
    float* out = (float*)d_out;

    hipMemsetAsync(out, 0, (size_t)out_size * sizeof(float), stream);

    const size_t frag_bytes = (size_t)(2 * W1FRAG + 2 * W2FRAG) * sizeof(unsigned short);
    unsigned short* w1h = (unsigned short*)d_ws;
    unsigned short* w1l = w1h + W1FRAG;
    unsigned short* w2h = w1l + W1FRAG;
    unsigned short* w2l = w2h + W2FRAG;

    const int NSCAN = (NN + 1023) / 1024;             // 25
    size_t o_cnt  = frag_bytes;
    size_t o_cur  = o_cnt + (size_t)NBIN_PAD * 4;
    size_t o_tot  = o_cur + (size_t)NBIN_PAD * 4;
    size_t o_toff = o_tot + 128;
    size_t o_perm = o_toff + 128;
    size_t need_sort = o_perm + (size_t)EDGES * 4;

    k_wfrag<<<(W1FRAG + W2FRAG + 255) / 256, 256, 0, stream>>>(W1, W2, w1h, w1l, w2h, w2l);

    if (ws_size >= need_sort) {
        unsigned* cnt  = (unsigned*)((char*)d_ws + o_cnt);
        unsigned* cur  = (unsigned*)((char*)d_ws + o_cur);
        unsigned* tot  = (unsigned*)((char*)d_ws + o_tot);
        unsigned* toff = (unsigned*)((char*)d_ws + o_toff);
        unsigned* perm = (unsigned*)((char*)d_ws + o_perm);
        hipMemsetAsync(cnt, 0, (size_t)NBIN_PAD * 4, stream);
        k_hist<<<(EDGES + 255) / 256, 256, 0, stream>>>(edst, cnt);
        k_scanA<<<NSCAN, 1024, 0, stream>>>(cnt, cur, tot);
        k_scanB<<<1, 64, 0, stream>>>(tot, toff, NSCAN);
        k_scanC<<<NSCAN, 1024, 0, stream>>>(cur, toff);
        k_perm<<<(EDGES + 255) / 256, 256, 0, stream>>>(edst, cur, perm);
        conv_fused<true><<<EDGES / EPA, 256, 0, stream>>>(
            esrc, edst, nemb, etype, w1h, w1l, w2h, w2l, perm, out);
    } else {
        conv_fused<false><<<EDGES / EPA, 256, 0, stream>>>(
            esrc, edst, nemb, etype, w1h, w1l, w2h, w2l, nullptr, out);
    }
}